// Round 1
// baseline (833.171 us; speedup 1.0000x reference)
//
#include <hip/hip_runtime.h>

#define Bc 8
#define Lc 1024
#define Dc 512
#define Hc 8
#define DHc 64
#define Mc (Bc*Lc)

__device__ __forceinline__ unsigned short f2bf(float f) {
    unsigned u = __float_as_uint(f);
    u += 0x7fffu + ((u >> 16) & 1u);          // round-to-nearest-even
    return (unsigned short)(u >> 16);
}
__device__ __forceinline__ unsigned pk2(float a, float b) {
    return (unsigned)f2bf(a) | ((unsigned)f2bf(b) << 16);
}
__device__ __forceinline__ float bflo(unsigned u) { return __uint_as_float(u << 16); }
__device__ __forceinline__ float bfhi(unsigned u) { return __uint_as_float(u & 0xffff0000u); }
__device__ __forceinline__ float bf2f(unsigned short s) { return __uint_as_float(((unsigned)s) << 16); }

// ---------------------------------------------------------------------------
// QKV projection: C = x @ W^T for W in {Wq,Wk,Wv}; x (8192,512), W (512,512).
// 128x128 tile, 256 threads, 8x8 microtile, K-chunk 32, fp32 LDS (c-major).
// Output layout (B,H,L,DH): out[((b*H+h)*L + l)*DH + dh]
// ---------------------------------------------------------------------------
__global__ __launch_bounds__(256, 2) void proj_qkv_kernel(
    const float* __restrict__ x,
    const float* __restrict__ Wq, const float* __restrict__ Wk,
    const float* __restrict__ Wv,
    float* __restrict__ qo, float* __restrict__ ko, float* __restrict__ vo)
{
    const float* W;
    float* out;
    if (blockIdx.z == 0)      { W = Wq; out = qo; }
    else if (blockIdx.z == 1) { W = Wk; out = ko; }
    else                      { W = Wv; out = vo; }

    __shared__ float As[32 * 132];   // As[cc][mm]
    __shared__ float Bs[32 * 132];   // Bs[cc][nn]

    const int t  = threadIdx.x;
    const int tx = t & 15, ty = t >> 4;
    const int m0 = blockIdx.y * 128;
    const int n0 = blockIdx.x * 128;
    const int lr = t >> 3;          // 0..31
    const int c4 = (t & 7) * 4;     // 0,4,...,28

    float acc[8][8];
    #pragma unroll
    for (int i = 0; i < 8; i++)
        #pragma unroll
        for (int j = 0; j < 8; j++) acc[i][j] = 0.f;

    for (int c0 = 0; c0 < Dc; c0 += 32) {
        __syncthreads();
        #pragma unroll
        for (int r = 0; r < 4; r++) {
            int ml = r * 32 + lr;
            float4 a = *(const float4*)&x[(size_t)(m0 + ml) * Dc + c0 + c4];
            As[(c4+0)*132 + ml] = a.x; As[(c4+1)*132 + ml] = a.y;
            As[(c4+2)*132 + ml] = a.z; As[(c4+3)*132 + ml] = a.w;
            float4 w = *(const float4*)&W[(size_t)(n0 + ml) * Dc + c0 + c4];
            Bs[(c4+0)*132 + ml] = w.x; Bs[(c4+1)*132 + ml] = w.y;
            Bs[(c4+2)*132 + ml] = w.z; Bs[(c4+3)*132 + ml] = w.w;
        }
        __syncthreads();
        #pragma unroll 4
        for (int cc = 0; cc < 32; cc++) {
            float4 a0 = *(const float4*)&As[cc*132 + ty*8];
            float4 a1 = *(const float4*)&As[cc*132 + ty*8 + 4];
            float4 b0 = *(const float4*)&Bs[cc*132 + tx*8];
            float4 b1 = *(const float4*)&Bs[cc*132 + tx*8 + 4];
            float av[8] = {a0.x,a0.y,a0.z,a0.w,a1.x,a1.y,a1.z,a1.w};
            float bv[8] = {b0.x,b0.y,b0.z,b0.w,b1.x,b1.y,b1.z,b1.w};
            #pragma unroll
            for (int i = 0; i < 8; i++)
                #pragma unroll
                for (int j = 0; j < 8; j++)
                    acc[i][j] += av[i] * bv[j];
        }
    }

    #pragma unroll
    for (int i = 0; i < 8; i++) {
        int m = m0 + ty*8 + i;
        int b = m >> 10, l = m & 1023;
        #pragma unroll
        for (int jc = 0; jc < 2; jc++) {
            int n  = n0 + tx*8 + jc*4;
            int h  = n >> 6, dh = n & 63;
            float4 v = make_float4(acc[i][jc*4+0], acc[i][jc*4+1],
                                   acc[i][jc*4+2], acc[i][jc*4+3]);
            *(float4*)&out[((size_t)((b*Hc + h)*Lc + l))*DHc + dh] = v;
        }
    }
}

// ---------------------------------------------------------------------------
// Output GEMM: out = attn @ Wo^T + bo.  attn (8192,512), Wo (512,512).
// ---------------------------------------------------------------------------
__global__ __launch_bounds__(256, 2) void out_gemm_kernel(
    const float* __restrict__ A, const float* __restrict__ W,
    const float* __restrict__ bias, float* __restrict__ out)
{
    __shared__ float As[32 * 132];
    __shared__ float Bs[32 * 132];

    const int t  = threadIdx.x;
    const int tx = t & 15, ty = t >> 4;
    const int m0 = blockIdx.y * 128;
    const int n0 = blockIdx.x * 128;
    const int lr = t >> 3;
    const int c4 = (t & 7) * 4;

    float acc[8][8];
    #pragma unroll
    for (int i = 0; i < 8; i++)
        #pragma unroll
        for (int j = 0; j < 8; j++) acc[i][j] = 0.f;

    for (int c0 = 0; c0 < Dc; c0 += 32) {
        __syncthreads();
        #pragma unroll
        for (int r = 0; r < 4; r++) {
            int ml = r * 32 + lr;
            float4 a = *(const float4*)&A[(size_t)(m0 + ml) * Dc + c0 + c4];
            As[(c4+0)*132 + ml] = a.x; As[(c4+1)*132 + ml] = a.y;
            As[(c4+2)*132 + ml] = a.z; As[(c4+3)*132 + ml] = a.w;
            float4 w = *(const float4*)&W[(size_t)(n0 + ml) * Dc + c0 + c4];
            Bs[(c4+0)*132 + ml] = w.x; Bs[(c4+1)*132 + ml] = w.y;
            Bs[(c4+2)*132 + ml] = w.z; Bs[(c4+3)*132 + ml] = w.w;
        }
        __syncthreads();
        #pragma unroll 4
        for (int cc = 0; cc < 32; cc++) {
            float4 a0 = *(const float4*)&As[cc*132 + ty*8];
            float4 a1 = *(const float4*)&As[cc*132 + ty*8 + 4];
            float4 b0 = *(const float4*)&Bs[cc*132 + tx*8];
            float4 b1 = *(const float4*)&Bs[cc*132 + tx*8 + 4];
            float av[8] = {a0.x,a0.y,a0.z,a0.w,a1.x,a1.y,a1.z,a1.w};
            float bv[8] = {b0.x,b0.y,b0.z,b0.w,b1.x,b1.y,b1.z,b1.w};
            #pragma unroll
            for (int i = 0; i < 8; i++)
                #pragma unroll
                for (int j = 0; j < 8; j++)
                    acc[i][j] += av[i] * bv[j];
        }
    }

    #pragma unroll
    for (int i = 0; i < 8; i++) {
        int m = m0 + ty*8 + i;
        #pragma unroll
        for (int jc = 0; jc < 2; jc++) {
            int n = n0 + tx*8 + jc*4;
            float4 bb = *(const float4*)&bias[n];
            float4 v = make_float4(acc[i][jc*4+0] + bb.x, acc[i][jc*4+1] + bb.y,
                                   acc[i][jc*4+2] + bb.z, acc[i][jc*4+3] + bb.w);
            *(float4*)&out[(size_t)m * Dc + n] = v;
        }
    }
}

// ---------------------------------------------------------------------------
// Flash attention with relative bias.
// s_rel[l,s] = q[l] . We[1023 - |l-s|]  computed per (64-l x 64-s) tile as a
// dense QE tile  qe[l][j2] = q[l] . We[e0+j2],  e0 = 960 - |l0-s0|,
// then gathered with j2 = 63 + |l0-s0| - |l-s|.
// Block = 256 thr (16x16), 4x4 microtile. fp32 accum; bf16 LDS tiles.
// LDS: qs fp32 16K + k 8.5K + v 8.5K + We/qe 16.5K = 50.7 KB (3 blocks/CU).
// ---------------------------------------------------------------------------
__global__ __launch_bounds__(256) void attn_kernel(
    const float* __restrict__ q, const float* __restrict__ k,
    const float* __restrict__ v, const float* __restrict__ We,
    float* __restrict__ attn)
{
    __shared__ float          qs[64 * 64];      // qs[d][l]
    __shared__ unsigned short ksu[64 * 68];     // k: [d][s]; later P^T: [s][l]
    __shared__ unsigned short vsu[64 * 68];     // v: [s][d]
    __shared__ unsigned short wesu[64 * 132];   // We: [d][j2]; later qe: [l][j2]

    const int t  = threadIdx.x;
    const int tx = t & 15, ty = t >> 4;
    const int bh = blockIdx.y;            // b*8 + h
    const int l0 = blockIdx.x * 64;

    const float* qb = q + (size_t)bh * (Lc * DHc);
    const float* kb = k + (size_t)bh * (Lc * DHc);
    const float* vb = v + (size_t)bh * (Lc * DHc);

    const int sl = t >> 2;          // 0..63  (row within tile for staging)
    const int d0 = (t & 3) * 16;    // 0,16,32,48

    // stage q tile once (transpose to d-major, fp32)
    #pragma unroll
    for (int c = 0; c < 4; c++) {
        float4 a = *(const float4*)&qb[(size_t)(l0 + sl) * DHc + d0 + 4*c];
        qs[(d0+4*c+0)*64 + sl] = a.x;
        qs[(d0+4*c+1)*64 + sl] = a.y;
        qs[(d0+4*c+2)*64 + sl] = a.z;
        qs[(d0+4*c+3)*64 + sl] = a.w;
    }

    float O[4][4], mrow[4], lsum[4];
    #pragma unroll
    for (int i = 0; i < 4; i++) {
        mrow[i] = -3.0e38f; lsum[i] = 0.f;
        #pragma unroll
        for (int j = 0; j < 4; j++) O[i][j] = 0.f;
    }

    for (int s0 = 0; s0 < Lc; s0 += 64) {
        const int c0  = l0 - s0;
        const int ac0 = c0 < 0 ? -c0 : c0;
        const int e0  = Lc - 64 - ac0;

        __syncthreads();   // prev-iter PV reads done before restaging
        // ---- stage k (d-major), v (s-major), We rows e0..e0+127 (d-major)
        #pragma unroll
        for (int c = 0; c < 4; c++) {
            float4 a = *(const float4*)&kb[(size_t)(s0 + sl) * DHc + d0 + 4*c];
            ksu[(d0+4*c+0)*68 + sl] = f2bf(a.x);
            ksu[(d0+4*c+1)*68 + sl] = f2bf(a.y);
            ksu[(d0+4*c+2)*68 + sl] = f2bf(a.z);
            ksu[(d0+4*c+3)*68 + sl] = f2bf(a.w);
            float4 b = *(const float4*)&vb[(size_t)(s0 + sl) * DHc + d0 + 4*c];
            *(uint2*)&vsu[sl*68 + d0 + 4*c] = make_uint2(pk2(b.x, b.y), pk2(b.z, b.w));
        }
        #pragma unroll
        for (int r = 0; r < 2; r++) {
            int j2 = r * 64 + sl;
            int e  = e0 + j2; if (e > Lc - 1) e = Lc - 1;   // clamped rows unused
            #pragma unroll
            for (int c = 0; c < 4; c++) {
                float4 a = *(const float4*)&We[(size_t)e * DHc + d0 + 4*c];
                wesu[(d0+4*c+0)*132 + j2] = f2bf(a.x);
                wesu[(d0+4*c+1)*132 + j2] = f2bf(a.y);
                wesu[(d0+4*c+2)*132 + j2] = f2bf(a.z);
                wesu[(d0+4*c+3)*132 + j2] = f2bf(a.w);
            }
        }
        __syncthreads();

        // ---- fused S (4x4) + QE (4x8) register GEMM over d
        float sacc[4][4], qe[4][8];
        #pragma unroll
        for (int i = 0; i < 4; i++) {
            #pragma unroll
            for (int j = 0; j < 4; j++) sacc[i][j] = 0.f;
            #pragma unroll
            for (int j = 0; j < 8; j++) qe[i][j] = 0.f;
        }
        #pragma unroll 4
        for (int d = 0; d < 64; d++) {
            float4 q4 = *(const float4*)&qs[d*64 + ty*4];
            uint2  ku = *(const uint2*)&ksu[d*68 + tx*4];
            uint2  wa = *(const uint2*)&wesu[d*132 + tx*8];
            uint2  wb = *(const uint2*)&wesu[d*132 + tx*8 + 4];
            float qv[4] = {q4.x, q4.y, q4.z, q4.w};
            float kv[4] = {bflo(ku.x), bfhi(ku.x), bflo(ku.y), bfhi(ku.y)};
            float wv[8] = {bflo(wa.x), bfhi(wa.x), bflo(wa.y), bfhi(wa.y),
                           bflo(wb.x), bfhi(wb.x), bflo(wb.y), bfhi(wb.y)};
            #pragma unroll
            for (int i = 0; i < 4; i++) {
                #pragma unroll
                for (int j = 0; j < 4; j++) sacc[i][j] += qv[i] * kv[j];
                #pragma unroll
                for (int j = 0; j < 8; j++) qe[i][j]   += qv[i] * wv[j];
            }
        }
        __syncthreads();   // all We/k reads done

        // ---- scatter qe tile into wesu as qes[l][j2] (bf16)
        #pragma unroll
        for (int i = 0; i < 4; i++) {
            int ll = ty*4 + i;
            *(uint2*)&wesu[ll*132 + tx*8]     = make_uint2(pk2(qe[i][0], qe[i][1]),
                                                           pk2(qe[i][2], qe[i][3]));
            *(uint2*)&wesu[ll*132 + tx*8 + 4] = make_uint2(pk2(qe[i][4], qe[i][5]),
                                                           pk2(qe[i][6], qe[i][7]));
        }
        __syncthreads();

        // ---- gather bias, online softmax
        float p[4][4];
        #pragma unroll
        for (int i = 0; i < 4; i++) {
            const int ll = ty*4 + i;
            float tv[4];
            #pragma unroll
            for (int j = 0; j < 4; j++) {
                int dls  = (ll - (tx*4 + j)) + c0;          // l - s (global)
                int adls = dls < 0 ? -dls : dls;
                int j2   = 63 + ac0 - adls;
                float bias = bf2f(wesu[ll*132 + j2]);
                tv[j] = 0.125f * (sacc[i][j] + bias);
            }
            float mloc = fmaxf(fmaxf(tv[0], tv[1]), fmaxf(tv[2], tv[3]));
            #pragma unroll
            for (int off = 1; off < 16; off <<= 1)
                mloc = fmaxf(mloc, __shfl_xor(mloc, off));
            float mnew = fmaxf(mrow[i], mloc);
            float al   = __expf(mrow[i] - mnew);
            float rs   = 0.f;
            #pragma unroll
            for (int j = 0; j < 4; j++) { p[i][j] = __expf(tv[j] - mnew); rs += p[i][j]; }
            #pragma unroll
            for (int off = 1; off < 16; off <<= 1)
                rs += __shfl_xor(rs, off);
            lsum[i] = lsum[i] * al + rs;
            mrow[i] = mnew;
            #pragma unroll
            for (int j = 0; j < 4; j++) O[i][j] *= al;
        }

        // ---- write P^T into ksu as Ps[s][l] (bf16)
        #pragma unroll
        for (int j = 0; j < 4; j++) {
            int s = tx*4 + j;
            *(uint2*)&ksu[s*68 + ty*4] = make_uint2(pk2(p[0][j], p[1][j]),
                                                    pk2(p[2][j], p[3][j]));
        }
        __syncthreads();

        // ---- O += P @ V
        #pragma unroll 4
        for (int s = 0; s < 64; s++) {
            uint2 pu = *(const uint2*)&ksu[s*68 + ty*4];
            uint2 vu = *(const uint2*)&vsu[s*68 + tx*4];
            float pv[4] = {bflo(pu.x), bfhi(pu.x), bflo(pu.y), bfhi(pu.y)};
            float vv[4] = {bflo(vu.x), bfhi(vu.x), bflo(vu.y), bfhi(vu.y)};
            #pragma unroll
            for (int i = 0; i < 4; i++)
                #pragma unroll
                for (int j = 0; j < 4; j++)
                    O[i][j] += pv[i] * vv[j];
        }
    }

    // ---- epilogue: normalize, write attn in (B,L,D) layout
    const int b = bh >> 3, h = bh & 7;
    #pragma unroll
    for (int i = 0; i < 4; i++) {
        float inv = 1.f / lsum[i];
        int l = l0 + ty*4 + i;
        float4 o = make_float4(O[i][0]*inv, O[i][1]*inv, O[i][2]*inv, O[i][3]*inv);
        *(float4*)&attn[((size_t)(b*Lc + l))*Dc + h*DHc + tx*4] = o;
    }
}

extern "C" void kernel_launch(void* const* d_in, const int* in_sizes, int n_in,
                              void* d_out, int out_size, void* d_ws, size_t ws_size,
                              hipStream_t stream)
{
    (void)in_sizes; (void)n_in; (void)out_size; (void)ws_size;
    const float* x  = (const float*)d_in[0];
    const float* Wq = (const float*)d_in[1];
    const float* Wk = (const float*)d_in[2];
    const float* Wv = (const float*)d_in[3];
    const float* We = (const float*)d_in[4];
    const float* Wo = (const float*)d_in[5];
    const float* bo = (const float*)d_in[6];

    float* ws = (float*)d_ws;
    const size_t NT = (size_t)Bc * Hc * Lc * DHc;   // 4,194,304 floats = 16 MB
    float* qw = ws;
    float* kw = ws + NT;
    float* vw = ws + 2 * NT;
    float* aw = ws + 3 * NT;   // attention output, (B,L,D) — total ws use 64 MB

    proj_qkv_kernel<<<dim3(4, 64, 3), 256, 0, stream>>>(x, Wq, Wk, Wv, qw, kw, vw);
    attn_kernel<<<dim3(16, 64), 256, 0, stream>>>(qw, kw, vw, We, aw);
    out_gemm_kernel<<<dim3(4, 64), 256, 0, stream>>>(aw, Wo, bo, (float*)d_out);
}

// Round 2
// 511.030 us; speedup vs baseline: 1.6304x; 1.6304x over previous
//
#include <hip/hip_runtime.h>

#define Lc 1024
#define Dc 512
#define Hc 8
#define DHc 64

typedef __attribute__((ext_vector_type(8))) short bf16x8;
typedef __attribute__((ext_vector_type(4))) float f32x4;

__device__ __forceinline__ unsigned short f2bf(float f) {
    unsigned u = __float_as_uint(f);
    u += 0x7fffu + ((u >> 16) & 1u);          // round-to-nearest-even
    return (unsigned short)(u >> 16);
}
__device__ __forceinline__ unsigned pk2(float a, float b) {
    return (unsigned)f2bf(a) | ((unsigned)f2bf(b) << 16);
}
__device__ __forceinline__ float bf2f(unsigned short s) { return __uint_as_float(((unsigned)s) << 16); }

// ---------------------------------------------------------------------------
// QKV projection: C = x @ W^T, fp32 compute, bf16 output in (B,H,L,DH).
// ---------------------------------------------------------------------------
__global__ __launch_bounds__(256, 2) void proj_qkv_kernel(
    const float* __restrict__ x,
    const float* __restrict__ Wq, const float* __restrict__ Wk,
    const float* __restrict__ Wv,
    unsigned short* __restrict__ qo, unsigned short* __restrict__ ko,
    unsigned short* __restrict__ vo)
{
    const float* W;
    unsigned short* out;
    if (blockIdx.z == 0)      { W = Wq; out = qo; }
    else if (blockIdx.z == 1) { W = Wk; out = ko; }
    else                      { W = Wv; out = vo; }

    __shared__ float As[32 * 132];
    __shared__ float Bs[32 * 132];

    const int t  = threadIdx.x;
    const int tx = t & 15, ty = t >> 4;
    const int m0 = blockIdx.y * 128;
    const int n0 = blockIdx.x * 128;
    const int lr = t >> 3;
    const int c4 = (t & 7) * 4;

    float acc[8][8];
    #pragma unroll
    for (int i = 0; i < 8; i++)
        #pragma unroll
        for (int j = 0; j < 8; j++) acc[i][j] = 0.f;

    for (int c0 = 0; c0 < Dc; c0 += 32) {
        __syncthreads();
        #pragma unroll
        for (int r = 0; r < 4; r++) {
            int ml = r * 32 + lr;
            float4 a = *(const float4*)&x[(size_t)(m0 + ml) * Dc + c0 + c4];
            As[(c4+0)*132 + ml] = a.x; As[(c4+1)*132 + ml] = a.y;
            As[(c4+2)*132 + ml] = a.z; As[(c4+3)*132 + ml] = a.w;
            float4 w = *(const float4*)&W[(size_t)(n0 + ml) * Dc + c0 + c4];
            Bs[(c4+0)*132 + ml] = w.x; Bs[(c4+1)*132 + ml] = w.y;
            Bs[(c4+2)*132 + ml] = w.z; Bs[(c4+3)*132 + ml] = w.w;
        }
        __syncthreads();
        #pragma unroll 4
        for (int cc = 0; cc < 32; cc++) {
            float4 a0 = *(const float4*)&As[cc*132 + ty*8];
            float4 a1 = *(const float4*)&As[cc*132 + ty*8 + 4];
            float4 b0 = *(const float4*)&Bs[cc*132 + tx*8];
            float4 b1 = *(const float4*)&Bs[cc*132 + tx*8 + 4];
            float av[8] = {a0.x,a0.y,a0.z,a0.w,a1.x,a1.y,a1.z,a1.w};
            float bv[8] = {b0.x,b0.y,b0.z,b0.w,b1.x,b1.y,b1.z,b1.w};
            #pragma unroll
            for (int i = 0; i < 8; i++)
                #pragma unroll
                for (int j = 0; j < 8; j++)
                    acc[i][j] += av[i] * bv[j];
        }
    }

    #pragma unroll
    for (int i = 0; i < 8; i++) {
        int m = m0 + ty*8 + i;
        int b = m >> 10, l = m & 1023;
        #pragma unroll
        for (int jc = 0; jc < 2; jc++) {
            int n  = n0 + tx*8 + jc*4;
            int h  = n >> 6, dh = n & 63;
            uint2 v = make_uint2(pk2(acc[i][jc*4+0], acc[i][jc*4+1]),
                                 pk2(acc[i][jc*4+2], acc[i][jc*4+3]));
            *(uint2*)&out[((size_t)((b*Hc + h)*Lc + l))*DHc + dh] = v;
        }
    }
}

// ---------------------------------------------------------------------------
// We -> bf16 conversion (1024x64)
// ---------------------------------------------------------------------------
__global__ void cvt_we_kernel(const float* __restrict__ We,
                              unsigned short* __restrict__ wet)
{
    int i = (blockIdx.x * 256 + threadIdx.x) * 4;
    float4 a = *(const float4*)&We[i];
    *(uint2*)&wet[i] = make_uint2(pk2(a.x, a.y), pk2(a.z, a.w));
}

// ---------------------------------------------------------------------------
// Output GEMM: out = attn @ Wo^T + bo (fp32).
// ---------------------------------------------------------------------------
__global__ __launch_bounds__(256, 2) void out_gemm_kernel(
    const float* __restrict__ A, const float* __restrict__ W,
    const float* __restrict__ bias, float* __restrict__ out)
{
    __shared__ float As[32 * 132];
    __shared__ float Bs[32 * 132];

    const int t  = threadIdx.x;
    const int tx = t & 15, ty = t >> 4;
    const int m0 = blockIdx.y * 128;
    const int n0 = blockIdx.x * 128;
    const int lr = t >> 3;
    const int c4 = (t & 7) * 4;

    float acc[8][8];
    #pragma unroll
    for (int i = 0; i < 8; i++)
        #pragma unroll
        for (int j = 0; j < 8; j++) acc[i][j] = 0.f;

    for (int c0 = 0; c0 < Dc; c0 += 32) {
        __syncthreads();
        #pragma unroll
        for (int r = 0; r < 4; r++) {
            int ml = r * 32 + lr;
            float4 a = *(const float4*)&A[(size_t)(m0 + ml) * Dc + c0 + c4];
            As[(c4+0)*132 + ml] = a.x; As[(c4+1)*132 + ml] = a.y;
            As[(c4+2)*132 + ml] = a.z; As[(c4+3)*132 + ml] = a.w;
            float4 w = *(const float4*)&W[(size_t)(n0 + ml) * Dc + c0 + c4];
            Bs[(c4+0)*132 + ml] = w.x; Bs[(c4+1)*132 + ml] = w.y;
            Bs[(c4+2)*132 + ml] = w.z; Bs[(c4+3)*132 + ml] = w.w;
        }
        __syncthreads();
        #pragma unroll 4
        for (int cc = 0; cc < 32; cc++) {
            float4 a0 = *(const float4*)&As[cc*132 + ty*8];
            float4 a1 = *(const float4*)&As[cc*132 + ty*8 + 4];
            float4 b0 = *(const float4*)&Bs[cc*132 + tx*8];
            float4 b1 = *(const float4*)&Bs[cc*132 + tx*8 + 4];
            float av[8] = {a0.x,a0.y,a0.z,a0.w,a1.x,a1.y,a1.z,a1.w};
            float bv[8] = {b0.x,b0.y,b0.z,b0.w,b1.x,b1.y,b1.z,b1.w};
            #pragma unroll
            for (int i = 0; i < 8; i++)
                #pragma unroll
                for (int j = 0; j < 8; j++)
                    acc[i][j] += av[i] * bv[j];
        }
    }

    #pragma unroll
    for (int i = 0; i < 8; i++) {
        int m = m0 + ty*8 + i;
        #pragma unroll
        for (int jc = 0; jc < 2; jc++) {
            int n = n0 + tx*8 + jc*4;
            float4 bb = *(const float4*)&bias[n];
            float4 v = make_float4(acc[i][jc*4+0] + bb.x, acc[i][jc*4+1] + bb.y,
                                   acc[i][jc*4+2] + bb.z, acc[i][jc*4+3] + bb.w);
            *(float4*)&out[(size_t)m * Dc + n] = v;
        }
    }
}

// ---------------------------------------------------------------------------
// MFMA flash attention with relative bias.
//  - 1 block = 4 waves, 64 q-rows; wave w owns rows 16w..16w+15.
//  - 16x16x32 bf16 MFMA. A-frag: A[m=lane&15][k=quad*8+j] (row-major in LDS);
//    B-frag: B stored [n][k] row-major.
//  - bias s_rel[l,s] = q[l].We[1023-|l-s|]; per s-tile: QE = Q.We_tile^T via
//    MFMA, round-trip through LDS, gather with j2 = 63+|l0-s0|-|l-s|.
//  - LDS 36.9 KB: wes(We/Q/QE overlay) + ks(K/P) + vts(V^T).
// ---------------------------------------------------------------------------
__global__ __launch_bounds__(256) void attn_mfma_kernel(
    const unsigned short* __restrict__ q, const unsigned short* __restrict__ k,
    const unsigned short* __restrict__ v, const unsigned short* __restrict__ wet,
    float* __restrict__ attn)
{
    __shared__ unsigned short wes[128 * 72];  // We [j2][d] / Q staging / QE [l][j2] stride 136
    __shared__ unsigned short ks [64 * 72];   // K [s][d]; reused as P [l][s]
    __shared__ unsigned short vts[64 * 72];   // V^T [dd][s]

    const int t    = threadIdx.x;
    const int lane = t & 63, w = t >> 6;
    const int lq   = lane >> 4, ln = lane & 15;
    const int bh   = blockIdx.y;
    const int l0   = blockIdx.x * 64;

    const unsigned short* qb = q + (size_t)bh * (Lc * DHc);
    const unsigned short* kb = k + (size_t)bh * (Lc * DHc);
    const unsigned short* vb = v + (size_t)bh * (Lc * DHc);

    // ---- stage Q (rows l0..l0+63) into wes, preload A-frags (iter-invariant)
    {
        int row = t >> 2, c8 = (t & 3) * 16;
        *(uint4*)&wes[row*72 + c8]     = *(const uint4*)&qb[(size_t)(l0+row)*64 + c8];
        *(uint4*)&wes[row*72 + c8 + 8] = *(const uint4*)&qb[(size_t)(l0+row)*64 + c8 + 8];
    }
    __syncthreads();
    bf16x8 qa[2];
    qa[0] = *(bf16x8*)&wes[(16*w + ln)*72 +  0 + lq*8];
    qa[1] = *(bf16x8*)&wes[(16*w + ln)*72 + 32 + lq*8];

    float mrow[4], lsum[4];
    f32x4 Ov[4];
    #pragma unroll
    for (int r = 0; r < 4; r++) { mrow[r] = -3.0e38f; lsum[r] = 0.f; }
    #pragma unroll
    for (int c = 0; c < 4; c++) Ov[c] = (f32x4){0.f, 0.f, 0.f, 0.f};

    for (int s0 = 0; s0 < Lc; s0 += 64) {
        const int c0  = l0 - s0;
        const int ac0 = c0 < 0 ? -c0 : c0;
        const int e0  = (Lc - 64) - ac0;

        __syncthreads();                       // prev-iter reads done
        // ---- stage K [s][d]
        {
            int s = t >> 2, c8 = (t & 3) * 16;
            *(uint4*)&ks[s*72 + c8]     = *(const uint4*)&kb[(size_t)(s0+s)*64 + c8];
            *(uint4*)&ks[s*72 + c8 + 8] = *(const uint4*)&kb[(size_t)(s0+s)*64 + c8 + 8];
        }
        // ---- stage V^T [dd][s] (bank-rotated scalar-pair writes)
        {
            int a = t & 7, s2 = (t >> 3) * 2;
            uint4 A  = *(const uint4*)&vb[(size_t)(s0+s2)  *64 + a*8];
            uint4 Bv = *(const uint4*)&vb[(size_t)(s0+s2+1)*64 + a*8];
            const unsigned short* Au = (const unsigned short*)&A;
            const unsigned short* Bu = (const unsigned short*)&Bv;
            #pragma unroll
            for (int i = 0; i < 8; i++) {
                int ii = (i + a) & 7;
                unsigned val = (unsigned)Au[ii] | ((unsigned)Bu[ii] << 16);
                *(unsigned*)&vts[(a*8 + ii)*72 + s2] = val;
            }
        }
        // ---- stage We rows e0..e0+127 as [j2][d]
        {
            int j2 = t >> 1, c8 = (t & 1) * 32;
            int e = e0 + j2; if (e > Lc - 1) e = Lc - 1;   // clamped rows unused
            #pragma unroll
            for (int i = 0; i < 4; i++)
                *(uint4*)&wes[j2*72 + c8 + 8*i] = *(const uint4*)&wet[(size_t)e*64 + c8 + 8*i];
        }
        __syncthreads();

        // ---- S = Q.K^T (4 tiles) and QE = Q.We^T (8 tiles), MFMA
        f32x4 sc[4], qec[8];
        #pragma unroll
        for (int c = 0; c < 4; c++) sc[c]  = (f32x4){0.f,0.f,0.f,0.f};
        #pragma unroll
        for (int c = 0; c < 8; c++) qec[c] = (f32x4){0.f,0.f,0.f,0.f};
        #pragma unroll
        for (int kk = 0; kk < 2; kk++) {
            #pragma unroll
            for (int c = 0; c < 4; c++) {
                bf16x8 bf = *(bf16x8*)&ks[(16*c + ln)*72 + kk*32 + lq*8];
                sc[c] = __builtin_amdgcn_mfma_f32_16x16x32_bf16(qa[kk], bf, sc[c], 0, 0, 0);
            }
            #pragma unroll
            for (int c = 0; c < 8; c++) {
                bf16x8 bf = *(bf16x8*)&wes[(16*c + ln)*72 + kk*32 + lq*8];
                qec[c] = __builtin_amdgcn_mfma_f32_16x16x32_bf16(qa[kk], bf, qec[c], 0, 0, 0);
            }
        }
        __syncthreads();                       // all wes(We) reads done

        // ---- QE C-regs -> wes as qes[l][j2] stride 136 (bf16)
        #pragma unroll
        for (int c = 0; c < 8; c++)
            #pragma unroll
            for (int r = 0; r < 4; r++)
                wes[(16*w + 4*lq + r)*136 + 16*c + ln] = f2bf(qec[c][r]);
        // (gather below reads only rows written by this wave; in-wave ds order
        //  is enforced by compiler lgkmcnt — no barrier needed)

        // ---- bias gather + online softmax
        float p[4][4];
        #pragma unroll
        for (int r = 0; r < 4; r++) {
            const int lr = 16*w + 4*lq + r;
            float tv[4];
            #pragma unroll
            for (int c = 0; c < 4; c++) {
                int d  = c0 + lr - (16*c + ln);          // l - s
                int ad = d < 0 ? -d : d;
                int j2 = 63 + ac0 - ad;
                float bias = bf2f(wes[lr*136 + j2]);
                tv[c] = 0.125f * (sc[c][r] + bias);
            }
            float mloc = fmaxf(fmaxf(tv[0], tv[1]), fmaxf(tv[2], tv[3]));
            #pragma unroll
            for (int off = 1; off < 16; off <<= 1)
                mloc = fmaxf(mloc, __shfl_xor(mloc, off));
            float mnew = fmaxf(mrow[r], mloc);
            float al   = __expf(mrow[r] - mnew);
            float rs   = 0.f;
            #pragma unroll
            for (int c = 0; c < 4; c++) { p[r][c] = __expf(tv[c] - mnew); rs += p[r][c]; }
            #pragma unroll
            for (int off = 1; off < 16; off <<= 1)
                rs += __shfl_xor(rs, off);
            lsum[r] = lsum[r] * al + rs;
            mrow[r] = mnew;
            #pragma unroll
            for (int c = 0; c < 4; c++) Ov[c][r] *= al;
        }

        // ---- P -> ks as [l][s] stride 72 (bf16); own-wave rows only
        #pragma unroll
        for (int r = 0; r < 4; r++)
            #pragma unroll
            for (int c = 0; c < 4; c++)
                ks[(16*w + 4*lq + r)*72 + 16*c + ln] = f2bf(p[r][c]);

        // ---- O += P @ V   (A-frags read own-wave rows; vts staged earlier)
        #pragma unroll
        for (int kk = 0; kk < 2; kk++) {
            bf16x8 pa = *(bf16x8*)&ks[(16*w + ln)*72 + kk*32 + lq*8];
            #pragma unroll
            for (int c = 0; c < 4; c++) {
                bf16x8 vf = *(bf16x8*)&vts[(16*c + ln)*72 + kk*32 + lq*8];
                Ov[c] = __builtin_amdgcn_mfma_f32_16x16x32_bf16(pa, vf, Ov[c], 0, 0, 0);
            }
        }
    }

    // ---- epilogue: normalize, write (B,L,D) fp32
    const int b = bh >> 3, h = bh & 7;
    #pragma unroll
    for (int r = 0; r < 4; r++) {
        float inv = 1.f / lsum[r];
        int l = l0 + 16*w + 4*lq + r;
        #pragma unroll
        for (int c = 0; c < 4; c++)
            attn[((size_t)(b*Lc + l))*Dc + h*DHc + 16*c + ln] = Ov[c][r] * inv;
    }
}

extern "C" void kernel_launch(void* const* d_in, const int* in_sizes, int n_in,
                              void* d_out, int out_size, void* d_ws, size_t ws_size,
                              hipStream_t stream)
{
    (void)in_sizes; (void)n_in; (void)out_size; (void)ws_size;
    const float* x  = (const float*)d_in[0];
    const float* Wq = (const float*)d_in[1];
    const float* Wk = (const float*)d_in[2];
    const float* Wv = (const float*)d_in[3];
    const float* We = (const float*)d_in[4];
    const float* Wo = (const float*)d_in[5];
    const float* bo = (const float*)d_in[6];

    const size_t NT = (size_t)8 * Hc * Lc * DHc;     // 4,194,304 elems
    unsigned short* qw  = (unsigned short*)d_ws;
    unsigned short* kw  = qw + NT;
    unsigned short* vw  = kw + NT;
    unsigned short* wet = vw + NT;                   // 65,536 elems
    float*          aw  = (float*)(wet + 65536);     // 16 MB, (B,L,D)

    proj_qkv_kernel<<<dim3(4, 64, 3), 256, 0, stream>>>(x, Wq, Wk, Wv, qw, kw, vw);
    cvt_we_kernel<<<64, 256, 0, stream>>>(We, wet);
    attn_mfma_kernel<<<dim3(16, 64), 256, 0, stream>>>(qw, kw, vw, wet, aw);
    out_gemm_kernel<<<dim3(4, 64), 256, 0, stream>>>(aw, Wo, bo, (float*)d_out);
}

// Round 3
// 301.348 us; speedup vs baseline: 2.7648x; 1.6958x over previous
//
#include <hip/hip_runtime.h>

#define Lc 1024
#define Dc 512
#define Hc 8
#define DHc 64

typedef __attribute__((ext_vector_type(8))) short bf16x8;
typedef __attribute__((ext_vector_type(4))) float f32x4;

typedef __attribute__((address_space(1))) const unsigned int guint;
typedef __attribute__((address_space(3))) unsigned int luint;

__device__ __forceinline__ void gload_lds16(const void* g, void* l) {
    __builtin_amdgcn_global_load_lds((guint*)g, (luint*)l, 16, 0, 0);
}

__device__ __forceinline__ unsigned short f2bf(float f) {
    unsigned u = __float_as_uint(f);
    u += 0x7fffu + ((u >> 16) & 1u);          // round-to-nearest-even
    return (unsigned short)(u >> 16);
}
__device__ __forceinline__ unsigned pk2(float a, float b) {
    return (unsigned)f2bf(a) | ((unsigned)f2bf(b) << 16);
}
__device__ __forceinline__ float bf2f(unsigned short s) { return __uint_as_float(((unsigned)s) << 16); }

// ---------------------------------------------------------------------------
// fp32 -> bf16 cast of x, Wq, Wk, Wv, Wo, We (one kernel, block-range routed)
// ---------------------------------------------------------------------------
__global__ void cvt_all_kernel(
    const float* __restrict__ x,  const float* __restrict__ Wq,
    const float* __restrict__ Wk, const float* __restrict__ Wv,
    const float* __restrict__ Wo, const float* __restrict__ We,
    unsigned short* __restrict__ xb,  unsigned short* __restrict__ wqb,
    unsigned short* __restrict__ wkb, unsigned short* __restrict__ wvb,
    unsigned short* __restrict__ wob, unsigned short* __restrict__ wet)
{
    int bid = blockIdx.x;
    const float* src; unsigned short* dst; size_t base;
    if      (bid < 4096) { src = x;  dst = xb;  base = (size_t)bid * 1024; }
    else if (bid < 4352) { src = Wq; dst = wqb; base = (size_t)(bid-4096) * 1024; }
    else if (bid < 4608) { src = Wk; dst = wkb; base = (size_t)(bid-4352) * 1024; }
    else if (bid < 4864) { src = Wv; dst = wvb; base = (size_t)(bid-4608) * 1024; }
    else if (bid < 5120) { src = Wo; dst = wob; base = (size_t)(bid-4864) * 1024; }
    else                 { src = We; dst = wet; base = (size_t)(bid-5120) * 1024; }
    size_t i = base + (size_t)threadIdx.x * 4;
    float4 a = *(const float4*)&src[i];
    *(uint2*)&dst[i] = make_uint2(pk2(a.x, a.y), pk2(a.z, a.w));
}

// ---------------------------------------------------------------------------
// QKV projection, bf16 MFMA: C = xb @ W^T (M=8192, N=512, K=512).
// m97 structure: 128x128 tile, BK=32, 4 waves 2x2, global_load_lds staging.
// Output bf16, (B,H,L,DH) layout.
// ---------------------------------------------------------------------------
__global__ __launch_bounds__(256, 3) void proj_mfma_kernel(
    const unsigned short* __restrict__ xb,
    const unsigned short* __restrict__ wq, const unsigned short* __restrict__ wk,
    const unsigned short* __restrict__ wv,
    unsigned short* __restrict__ qo, unsigned short* __restrict__ ko,
    unsigned short* __restrict__ vo)
{
    const unsigned short* W; unsigned short* out;
    if (blockIdx.z == 0)      { W = wq; out = qo; }
    else if (blockIdx.z == 1) { W = wk; out = ko; }
    else                      { W = wv; out = vo; }

    __shared__ unsigned short As[128 * 32];   // [m][k], unpadded (DMA layout)
    __shared__ unsigned short Bs[128 * 32];   // [n][k]

    const int t = threadIdx.x;
    const int lane = t & 63, w = t >> 6;
    const int lq = lane >> 4, ln = lane & 15;
    const int m0 = blockIdx.y * 128, n0 = blockIdx.x * 128;
    const int wm = (w & 1) * 64, wn = (w >> 1) * 64;
    const int srow = t >> 2, scol = (t & 3) * 8;

    f32x4 acc[4][4];
    #pragma unroll
    for (int i = 0; i < 4; i++)
        #pragma unroll
        for (int j = 0; j < 4; j++) acc[i][j] = (f32x4){0.f,0.f,0.f,0.f};

    for (int c0 = 0; c0 < 512; c0 += 32) {
        __syncthreads();
        gload_lds16(&xb[(size_t)(m0 +      srow) * 512 + c0 + scol], &As[srow * 32 + scol]);
        gload_lds16(&xb[(size_t)(m0 + 64 + srow) * 512 + c0 + scol], &As[(64 + srow) * 32 + scol]);
        gload_lds16(&W [(size_t)(n0 +      srow) * 512 + c0 + scol], &Bs[srow * 32 + scol]);
        gload_lds16(&W [(size_t)(n0 + 64 + srow) * 512 + c0 + scol], &Bs[(64 + srow) * 32 + scol]);
        __syncthreads();

        bf16x8 af[4], bf[4];
        #pragma unroll
        for (int i = 0; i < 4; i++)
            af[i] = *(bf16x8*)&As[(wm + 16*i + ln) * 32 + lq * 8];
        #pragma unroll
        for (int j = 0; j < 4; j++)
            bf[j] = *(bf16x8*)&Bs[(wn + 16*j + ln) * 32 + lq * 8];
        #pragma unroll
        for (int i = 0; i < 4; i++)
            #pragma unroll
            for (int j = 0; j < 4; j++)
                acc[i][j] = __builtin_amdgcn_mfma_f32_16x16x32_bf16(af[i], bf[j], acc[i][j], 0, 0, 0);
    }

    #pragma unroll
    for (int i = 0; i < 4; i++) {
        #pragma unroll
        for (int r = 0; r < 4; r++) {
            int m = m0 + wm + 16*i + 4*lq + r;
            int b = m >> 10, l = m & 1023;
            #pragma unroll
            for (int j = 0; j < 4; j++) {
                int n = n0 + wn + 16*j + ln;
                int h = n >> 6, dh = n & 63;
                out[((size_t)((b*Hc + h)*Lc + l))*DHc + dh] = f2bf(acc[i][j][r]);
            }
        }
    }
}

// ---------------------------------------------------------------------------
// Output GEMM, bf16 MFMA: out = awb @ Wo^T + bo (fp32 out, M=8192,N=512,K=512)
// ---------------------------------------------------------------------------
__global__ __launch_bounds__(256, 3) void out_mfma_kernel(
    const unsigned short* __restrict__ A, const unsigned short* __restrict__ W,
    const float* __restrict__ bias, float* __restrict__ out)
{
    __shared__ unsigned short As[128 * 32];
    __shared__ unsigned short Bs[128 * 32];

    const int t = threadIdx.x;
    const int lane = t & 63, w = t >> 6;
    const int lq = lane >> 4, ln = lane & 15;
    const int m0 = blockIdx.y * 128, n0 = blockIdx.x * 128;
    const int wm = (w & 1) * 64, wn = (w >> 1) * 64;
    const int srow = t >> 2, scol = (t & 3) * 8;

    f32x4 acc[4][4];
    #pragma unroll
    for (int i = 0; i < 4; i++)
        #pragma unroll
        for (int j = 0; j < 4; j++) acc[i][j] = (f32x4){0.f,0.f,0.f,0.f};

    for (int c0 = 0; c0 < 512; c0 += 32) {
        __syncthreads();
        gload_lds16(&A[(size_t)(m0 +      srow) * 512 + c0 + scol], &As[srow * 32 + scol]);
        gload_lds16(&A[(size_t)(m0 + 64 + srow) * 512 + c0 + scol], &As[(64 + srow) * 32 + scol]);
        gload_lds16(&W[(size_t)(n0 +      srow) * 512 + c0 + scol], &Bs[srow * 32 + scol]);
        gload_lds16(&W[(size_t)(n0 + 64 + srow) * 512 + c0 + scol], &Bs[(64 + srow) * 32 + scol]);
        __syncthreads();

        bf16x8 af[4], bf[4];
        #pragma unroll
        for (int i = 0; i < 4; i++)
            af[i] = *(bf16x8*)&As[(wm + 16*i + ln) * 32 + lq * 8];
        #pragma unroll
        for (int j = 0; j < 4; j++)
            bf[j] = *(bf16x8*)&Bs[(wn + 16*j + ln) * 32 + lq * 8];
        #pragma unroll
        for (int i = 0; i < 4; i++)
            #pragma unroll
            for (int j = 0; j < 4; j++)
                acc[i][j] = __builtin_amdgcn_mfma_f32_16x16x32_bf16(af[i], bf[j], acc[i][j], 0, 0, 0);
    }

    float bb[4];
    #pragma unroll
    for (int j = 0; j < 4; j++) bb[j] = bias[n0 + wn + 16*j + ln];

    #pragma unroll
    for (int i = 0; i < 4; i++) {
        #pragma unroll
        for (int r = 0; r < 4; r++) {
            int m = m0 + wm + 16*i + 4*lq + r;
            #pragma unroll
            for (int j = 0; j < 4; j++) {
                int n = n0 + wn + 16*j + ln;
                out[(size_t)m * Dc + n] = acc[i][j][r] + bb[j];
            }
        }
    }
}

// ---------------------------------------------------------------------------
// MFMA flash attention with relative bias (unchanged from R2 except bf16 out).
// ---------------------------------------------------------------------------
__global__ __launch_bounds__(256) void attn_mfma_kernel(
    const unsigned short* __restrict__ q, const unsigned short* __restrict__ k,
    const unsigned short* __restrict__ v, const unsigned short* __restrict__ wet,
    unsigned short* __restrict__ attn)
{
    __shared__ unsigned short wes[128 * 72];  // We [j2][d] / Q staging / QE [l][j2] stride 136
    __shared__ unsigned short ks [64 * 72];   // K [s][d]; reused as P [l][s]
    __shared__ unsigned short vts[64 * 72];   // V^T [dd][s]

    const int t    = threadIdx.x;
    const int lane = t & 63, w = t >> 6;
    const int lq   = lane >> 4, ln = lane & 15;
    const int bh   = blockIdx.y;
    const int l0   = blockIdx.x * 64;

    const unsigned short* qb = q + (size_t)bh * (Lc * DHc);
    const unsigned short* kb = k + (size_t)bh * (Lc * DHc);
    const unsigned short* vb = v + (size_t)bh * (Lc * DHc);

    {
        int row = t >> 2, c8 = (t & 3) * 16;
        *(uint4*)&wes[row*72 + c8]     = *(const uint4*)&qb[(size_t)(l0+row)*64 + c8];
        *(uint4*)&wes[row*72 + c8 + 8] = *(const uint4*)&qb[(size_t)(l0+row)*64 + c8 + 8];
    }
    __syncthreads();
    bf16x8 qa[2];
    qa[0] = *(bf16x8*)&wes[(16*w + ln)*72 +  0 + lq*8];
    qa[1] = *(bf16x8*)&wes[(16*w + ln)*72 + 32 + lq*8];

    float mrow[4], lsum[4];
    f32x4 Ov[4];
    #pragma unroll
    for (int r = 0; r < 4; r++) { mrow[r] = -3.0e38f; lsum[r] = 0.f; }
    #pragma unroll
    for (int c = 0; c < 4; c++) Ov[c] = (f32x4){0.f, 0.f, 0.f, 0.f};

    for (int s0 = 0; s0 < Lc; s0 += 64) {
        const int c0  = l0 - s0;
        const int ac0 = c0 < 0 ? -c0 : c0;
        const int e0  = (Lc - 64) - ac0;

        __syncthreads();
        {
            int s = t >> 2, c8 = (t & 3) * 16;
            *(uint4*)&ks[s*72 + c8]     = *(const uint4*)&kb[(size_t)(s0+s)*64 + c8];
            *(uint4*)&ks[s*72 + c8 + 8] = *(const uint4*)&kb[(size_t)(s0+s)*64 + c8 + 8];
        }
        {
            int a = t & 7, s2 = (t >> 3) * 2;
            uint4 A  = *(const uint4*)&vb[(size_t)(s0+s2)  *64 + a*8];
            uint4 Bv = *(const uint4*)&vb[(size_t)(s0+s2+1)*64 + a*8];
            const unsigned short* Au = (const unsigned short*)&A;
            const unsigned short* Bu = (const unsigned short*)&Bv;
            #pragma unroll
            for (int i = 0; i < 8; i++) {
                int ii = (i + a) & 7;
                unsigned val = (unsigned)Au[ii] | ((unsigned)Bu[ii] << 16);
                *(unsigned*)&vts[(a*8 + ii)*72 + s2] = val;
            }
        }
        {
            int j2 = t >> 1, c8 = (t & 1) * 32;
            int e = e0 + j2; if (e > Lc - 1) e = Lc - 1;
            #pragma unroll
            for (int i = 0; i < 4; i++)
                *(uint4*)&wes[j2*72 + c8 + 8*i] = *(const uint4*)&wet[(size_t)e*64 + c8 + 8*i];
        }
        __syncthreads();

        f32x4 sc[4], qec[8];
        #pragma unroll
        for (int c = 0; c < 4; c++) sc[c]  = (f32x4){0.f,0.f,0.f,0.f};
        #pragma unroll
        for (int c = 0; c < 8; c++) qec[c] = (f32x4){0.f,0.f,0.f,0.f};
        #pragma unroll
        for (int kk = 0; kk < 2; kk++) {
            #pragma unroll
            for (int c = 0; c < 4; c++) {
                bf16x8 bf = *(bf16x8*)&ks[(16*c + ln)*72 + kk*32 + lq*8];
                sc[c] = __builtin_amdgcn_mfma_f32_16x16x32_bf16(qa[kk], bf, sc[c], 0, 0, 0);
            }
            #pragma unroll
            for (int c = 0; c < 8; c++) {
                bf16x8 bf = *(bf16x8*)&wes[(16*c + ln)*72 + kk*32 + lq*8];
                qec[c] = __builtin_amdgcn_mfma_f32_16x16x32_bf16(qa[kk], bf, qec[c], 0, 0, 0);
            }
        }
        __syncthreads();

        #pragma unroll
        for (int c = 0; c < 8; c++)
            #pragma unroll
            for (int r = 0; r < 4; r++)
                wes[(16*w + 4*lq + r)*136 + 16*c + ln] = f2bf(qec[c][r]);

        float p[4][4];
        #pragma unroll
        for (int r = 0; r < 4; r++) {
            const int lr = 16*w + 4*lq + r;
            float tv[4];
            #pragma unroll
            for (int c = 0; c < 4; c++) {
                int d  = c0 + lr - (16*c + ln);
                int ad = d < 0 ? -d : d;
                int j2 = 63 + ac0 - ad;
                float bias = bf2f(wes[lr*136 + j2]);
                tv[c] = 0.125f * (sc[c][r] + bias);
            }
            float mloc = fmaxf(fmaxf(tv[0], tv[1]), fmaxf(tv[2], tv[3]));
            #pragma unroll
            for (int off = 1; off < 16; off <<= 1)
                mloc = fmaxf(mloc, __shfl_xor(mloc, off));
            float mnew = fmaxf(mrow[r], mloc);
            float al   = __expf(mrow[r] - mnew);
            float rs   = 0.f;
            #pragma unroll
            for (int c = 0; c < 4; c++) { p[r][c] = __expf(tv[c] - mnew); rs += p[r][c]; }
            #pragma unroll
            for (int off = 1; off < 16; off <<= 1)
                rs += __shfl_xor(rs, off);
            lsum[r] = lsum[r] * al + rs;
            mrow[r] = mnew;
            #pragma unroll
            for (int c = 0; c < 4; c++) Ov[c][r] *= al;
        }

        #pragma unroll
        for (int r = 0; r < 4; r++)
            #pragma unroll
            for (int c = 0; c < 4; c++)
                ks[(16*w + 4*lq + r)*72 + 16*c + ln] = f2bf(p[r][c]);

        #pragma unroll
        for (int kk = 0; kk < 2; kk++) {
            bf16x8 pa = *(bf16x8*)&ks[(16*w + ln)*72 + kk*32 + lq*8];
            #pragma unroll
            for (int c = 0; c < 4; c++) {
                bf16x8 vf = *(bf16x8*)&vts[(16*c + ln)*72 + kk*32 + lq*8];
                Ov[c] = __builtin_amdgcn_mfma_f32_16x16x32_bf16(pa, vf, Ov[c], 0, 0, 0);
            }
        }
    }

    const int b = bh >> 3, h = bh & 7;
    #pragma unroll
    for (int r = 0; r < 4; r++) {
        float inv = 1.f / lsum[r];
        int l = l0 + 16*w + 4*lq + r;
        #pragma unroll
        for (int c = 0; c < 4; c++)
            attn[((size_t)(b*Lc + l))*Dc + h*DHc + 16*c + ln] = f2bf(Ov[c][r] * inv);
    }
}

extern "C" void kernel_launch(void* const* d_in, const int* in_sizes, int n_in,
                              void* d_out, int out_size, void* d_ws, size_t ws_size,
                              hipStream_t stream)
{
    (void)in_sizes; (void)n_in; (void)out_size; (void)ws_size;
    const float* x  = (const float*)d_in[0];
    const float* Wq = (const float*)d_in[1];
    const float* Wk = (const float*)d_in[2];
    const float* Wv = (const float*)d_in[3];
    const float* We = (const float*)d_in[4];
    const float* Wo = (const float*)d_in[5];
    const float* bo = (const float*)d_in[6];

    const size_t NT = (size_t)8 * Hc * Lc * DHc;     // 4,194,304 elems
    unsigned short* qw  = (unsigned short*)d_ws;
    unsigned short* kw  = qw  + NT;
    unsigned short* vw  = kw  + NT;
    unsigned short* xbf = vw  + NT;
    unsigned short* awb = xbf + NT;                  // attn out bf16, (B,L,D)
    unsigned short* wqb = awb + NT;
    unsigned short* wkb = wqb + 262144;
    unsigned short* wvb = wkb + 262144;
    unsigned short* wob = wvb + 262144;
    unsigned short* wet = wob + 262144;              // + 65536

    cvt_all_kernel<<<5184, 256, 0, stream>>>(x, Wq, Wk, Wv, Wo, We,
                                             xbf, wqb, wkb, wvb, wob, wet);
    proj_mfma_kernel<<<dim3(4, 64, 3), 256, 0, stream>>>(xbf, wqb, wkb, wvb, qw, kw, vw);
    attn_mfma_kernel<<<dim3(16, 64), 256, 0, stream>>>(qw, kw, vw, wet, awb);
    out_mfma_kernel<<<dim3(4, 64), 256, 0, stream>>>(awb, wob, bo, (float*)d_out);
}